// Round 2
// baseline (714.775 us; speedup 1.0000x reference)
//
#include <hip/hip_runtime.h>
#include <hip/hip_bf16.h>
#include <cstdint>
#include <cstddef>

typedef short bf16x8 __attribute__((ext_vector_type(8)));
typedef float f32x4 __attribute__((ext_vector_type(4)));
typedef unsigned short u16x4v __attribute__((ext_vector_type(4)));

__device__ __forceinline__ float bf2f(unsigned short u) {
  union { unsigned int u; float f; } v; v.u = ((unsigned int)u) << 16; return v.f;
}
__device__ __forceinline__ unsigned short f2bf(float f) {
  union { float f; unsigned int u; } v; v.f = f;
  unsigned int r = v.u + 0x7fffu + ((v.u >> 16) & 1u);
  return (unsigned short)(r >> 16);
}
__device__ __forceinline__ int pack2(float a, float b) {
  return (int)f2bf(a) | ((int)f2bf(b) << 16);
}

// ---------------- weight transpose + f32->bf16: Wt[n][k] = bf16(W[k][n]) ----------------
__global__ __launch_bounds__(256) void convert_transpose(
    const float* __restrict__ in, unsigned short* __restrict__ out,
    int K, int Ncol) {
  int idx = blockIdx.x * 256 + threadIdx.x;
  if (idx < K * Ncol) {
    int k = idx / Ncol, n = idx % Ncol;
    out[n * K + k] = f2bf(in[idx]);
  }
}

// ---------------- GEMM: C[M,Ncol] = A[M,K] @ Wt[Ncol,K]^T (f32 acc, bf16 out)
// A is f32 (AF32=true) or bf16 (false). blockIdx.z selects (BtL,outL)/(BtR,outR).
template<int BN, int WAVES_M, int WAVES_N, bool AF32>
__global__ __launch_bounds__(256) void gemm_dual(
    const void* __restrict__ Av,
    const unsigned short* __restrict__ BtL, const unsigned short* __restrict__ BtR,
    unsigned short* __restrict__ outL, unsigned short* __restrict__ outR,
    int M, int K, int Ncol) {
  constexpr int BM = 128, BK = 64;
  constexpr int WTM = BM / WAVES_M, WTN = BN / WAVES_N;
  constexpr int MR = WTM / 16, NR = WTN / 16;
  const unsigned short* __restrict__ Bt = blockIdx.z ? BtR : BtL;
  unsigned short* __restrict__ outp = blockIdx.z ? outR : outL;

  __shared__ alignas(16) unsigned short lAt[BM * BK];
  __shared__ alignas(16) unsigned short lBt[BN * BK];

  int t = threadIdx.x;
  int lane = t & 63, wid = t >> 6;
  int wm = wid / WAVES_N, wn = wid % WAVES_N;
  int rowBase = blockIdx.x * BM;
  int colBase = blockIdx.y * BN;

  f32x4 acc[MR][NR] = {};

  for (int k0 = 0; k0 < K; k0 += BK) {
    // stage A tile [BM][BK] as bf16, 16B chunks, XOR swizzle on chunk index
    #pragma unroll
    for (int p = 0; p < (BM * 8) / 256; ++p) {
      int lin = p * 256 + t;
      int row = lin >> 3, c = lin & 7;
      int gr = rowBase + row;
      int4 w = make_int4(0, 0, 0, 0);
      if constexpr (AF32) {
        const float* A = (const float*)Av;
        if (gr < M) {
          const float* ap = A + (size_t)gr * K + k0 + c * 8;
          f32x4 f0 = *reinterpret_cast<const f32x4*>(ap);
          f32x4 f1 = *reinterpret_cast<const f32x4*>(ap + 4);
          w.x = pack2(f0[0], f0[1]); w.y = pack2(f0[2], f0[3]);
          w.z = pack2(f1[0], f1[1]); w.w = pack2(f1[2], f1[3]);
        }
      } else {
        const unsigned short* A = (const unsigned short*)Av;
        if (gr < M) w = *reinterpret_cast<const int4*>(A + (size_t)gr * K + k0 + c * 8);
      }
      *reinterpret_cast<int4*>(&lAt[row * 64 + ((c ^ (row & 7)) * 8)]) = w;
    }
    // stage B tile [BN][BK] from Wt (bf16, rows = output cols, contiguous K)
    #pragma unroll
    for (int p = 0; p < (BN * 8) / 256; ++p) {
      int lin = p * 256 + t;
      int row = lin >> 3, c = lin & 7;
      int4 v = *reinterpret_cast<const int4*>(Bt + (size_t)(colBase + row) * K + k0 + c * 8);
      *reinterpret_cast<int4*>(&lBt[row * 64 + ((c ^ (row & 7)) * 8)]) = v;
    }
    __syncthreads();
    #pragma unroll
    for (int kk = 0; kk < 2; ++kk) {
      bf16x8 af[MR], bfr[NR];
      int cidx = kk * 4 + (lane >> 4);
      #pragma unroll
      for (int mi = 0; mi < MR; ++mi) {
        int row = wm * WTM + mi * 16 + (lane & 15);
        af[mi] = *reinterpret_cast<const bf16x8*>(&lAt[row * 64 + ((cidx ^ (row & 7)) * 8)]);
      }
      #pragma unroll
      for (int ni = 0; ni < NR; ++ni) {
        int row = wn * WTN + ni * 16 + (lane & 15);
        bfr[ni] = *reinterpret_cast<const bf16x8*>(&lBt[row * 64 + ((cidx ^ (row & 7)) * 8)]);
      }
      #pragma unroll
      for (int mi = 0; mi < MR; ++mi)
        #pragma unroll
        for (int ni = 0; ni < NR; ++ni)
          acc[mi][ni] = __builtin_amdgcn_mfma_f32_16x16x32_bf16(af[mi], bfr[ni], acc[mi][ni], 0, 0, 0);
    }
    __syncthreads();
  }
  // epilogue: C/D layout col=lane&15, row=(lane>>4)*4+r
  #pragma unroll
  for (int mi = 0; mi < MR; ++mi)
    #pragma unroll
    for (int ni = 0; ni < NR; ++ni) {
      int col = colBase + wn * WTN + ni * 16 + (lane & 15);
      #pragma unroll
      for (int r = 0; r < 4; ++r) {
        int row = rowBase + wm * WTM + mi * 16 + (lane >> 4) * 4 + r;
        if (row < M) outp[(size_t)row * Ncol + col] = f2bf(acc[mi][ni][r]);
      }
    }
}

// ---------------- CSR build ----------------
__global__ __launch_bounds__(256) void hist_kernel(const int* __restrict__ dst, int* __restrict__ counts, int E) {
  int e = blockIdx.x * 256 + threadIdx.x;
  if (e < E) atomicAdd(&counts[dst[e]], 1);
}

__global__ __launch_bounds__(256) void scan_block(const int* __restrict__ in, int* __restrict__ out,
                                                  int* __restrict__ sums, int n) {
  int i = blockIdx.x * 256 + threadIdx.x;
  int lane = threadIdx.x & 63, wid = threadIdx.x >> 6;
  int v = (i < n) ? in[i] : 0;
  int s = v;
  #pragma unroll
  for (int d = 1; d < 64; d <<= 1) { int tt = __shfl_up(s, d); if (lane >= d) s += tt; }
  __shared__ int wsum[4];
  if (lane == 63) wsum[wid] = s;
  __syncthreads();
  int off = 0;
  for (int w = 0; w < wid; ++w) off += wsum[w];
  if (i < n) out[i] = off + s - v;  // exclusive
  if (threadIdx.x == 255) sums[blockIdx.x] = off + s;
}

__global__ __launch_bounds__(256) void scan_add(int* __restrict__ rs, const int* __restrict__ boffs,
                                                int* __restrict__ cursor, int n, int E) {
  int i = blockIdx.x * 256 + threadIdx.x;
  if (i < n) {
    int v = rs[i] + boffs[blockIdx.x];
    rs[i] = v;
    cursor[i] = v;
  }
  if (i == 0) rs[n] = E;
}

__global__ __launch_bounds__(256) void scatter_kernel(const int* __restrict__ src, const int* __restrict__ dst,
                                                      int* __restrict__ cursor, int* __restrict__ csr, int E) {
  int e = blockIdx.x * 256 + threadIdx.x;
  if (e < E) {
    int p = atomicAdd(&cursor[dst[e]], 1);
    csr[p] = src[e];
  }
}

// ---------------- edge aggregation: one wave per dst node, online softmax ----------------
template<int H, bool SELF, bool RELU>
__global__ __launch_bounds__(256) void edge_agg(
    const unsigned short* __restrict__ xl, const unsigned short* __restrict__ xr,
    const float* __restrict__ att, const float* __restrict__ bias,
    const int* __restrict__ rowstart, const int* __restrict__ csr,
    unsigned short* __restrict__ out, int N) {
  constexpr int F = H * 64;
  constexpr int VEC = F / 64;      // channels per lane
  constexpr int GROUP = 64 / H;    // lanes per head
  int wave = threadIdx.x >> 6, lane = threadIdx.x & 63;
  int node = blockIdx.x * 4 + wave;
  if (node >= N) return;

  float attv[VEC], xrv[VEC], acc[VEC];
  if constexpr (VEC == 4) {
    f32x4 a4 = *reinterpret_cast<const f32x4*>(att + lane * 4);
    u16x4v r4 = *reinterpret_cast<const u16x4v*>(xr + (size_t)node * F + lane * 4);
    #pragma unroll
    for (int j = 0; j < 4; ++j) { attv[j] = a4[j]; xrv[j] = bf2f(r4[j]); acc[j] = 0.f; }
  } else {
    attv[0] = att[lane]; xrv[0] = bf2f(xr[(size_t)node * F + lane]); acc[0] = 0.f;
  }

  float m = -INFINITY, l = 0.f;
  int s0 = rowstart[node], s1 = rowstart[node + 1];
  int end = s1 + (SELF ? 1 : 0);
  for (int i = s0; i < end; ++i) {
    int s = (i < s1) ? csr[i] : node;
    float xlv[VEC];
    if constexpr (VEC == 4) {
      u16x4v v = *reinterpret_cast<const u16x4v*>(xl + (size_t)s * F + lane * 4);
      #pragma unroll
      for (int j = 0; j < 4; ++j) xlv[j] = bf2f(v[j]);
    } else {
      xlv[0] = bf2f(xl[(size_t)s * F + lane]);
    }
    float p = 0.f;
    #pragma unroll
    for (int j = 0; j < VEC; ++j) {
      float tv = xlv[j] + xrv[j];
      tv = fmaxf(tv, 0.2f * tv);       // leaky_relu, slope 0.2
      p = fmaf(tv, attv[j], p);
    }
    #pragma unroll
    for (int msk = 1; msk < GROUP; msk <<= 1) p += __shfl_xor(p, msk);
    float mn = fmaxf(m, p);
    float sc = __expf(m - mn);         // m=-inf first iter -> 0
    float w  = __expf(p - mn);
    l = fmaf(l, sc, w);
    #pragma unroll
    for (int j = 0; j < VEC; ++j) acc[j] = fmaf(acc[j], sc, w * xlv[j]);
    m = mn;
  }
  float rec = 1.f / (l + 1e-16f);
  unsigned short ov[VEC];
  #pragma unroll
  for (int j = 0; j < VEC; ++j) {
    float o = fmaf(acc[j], rec, bias[lane * VEC + j]);
    if (RELU) o = fmaxf(o, 0.f);
    ov[j] = f2bf(o);
  }
  if constexpr (VEC == 4) {
    u16x4v w4;
    #pragma unroll
    for (int j = 0; j < 4; ++j) w4[j] = ov[j];
    *reinterpret_cast<u16x4v*>(out + (size_t)node * F + lane * 4) = w4;
  } else {
    out[(size_t)node * F + lane] = ov[0];
  }
}

// ---------------- global mean pool (atomic) ----------------
__global__ __launch_bounds__(256) void pool_kernel(const unsigned short* __restrict__ h,
                                                   const int* __restrict__ batch,
                                                   float* __restrict__ gsum, int* __restrict__ gcnt, int N) {
  int wave = threadIdx.x >> 6, lane = threadIdx.x & 63;
  int node = blockIdx.x * 4 + wave;
  if (node >= N) return;
  int b = batch[node];
  atomicAdd(&gsum[(size_t)b * 64 + lane], bf2f(h[(size_t)node * 64 + lane]));
  if (lane == 0) atomicAdd(&gcnt[b], 1);
}

// ---------------- MLP head + softmax: one wave per graph (all f32) ----------------
__global__ __launch_bounds__(256) void mlp_kernel(
    const float* __restrict__ gsum, const int* __restrict__ gcnt,
    const float* __restrict__ w1, const float* __restrict__ b1,
    const float* __restrict__ w2, const float* __restrict__ b2,
    const float* __restrict__ w3, const float* __restrict__ b3,
    float* __restrict__ out, int G) {
  int wave = threadIdx.x >> 6, lane = threadIdx.x & 63;
  int r = blockIdx.x * 4 + wave;
  bool ok = r < G;
  __shared__ float sh[4][64];
  float xv = 0.f;
  if (ok) {
    float cnt = fmaxf((float)gcnt[r], 1.0f);
    xv = gsum[(size_t)r * 64 + lane] / cnt;
  }
  sh[wave][lane] = xv;
  __syncthreads();
  float h1 = b1[lane];
  for (int k = 0; k < 64; ++k) h1 = fmaf(sh[wave][k], w1[k * 64 + lane], h1);
  h1 = fmaxf(h1, 0.f);
  __syncthreads();
  sh[wave][lane] = h1;
  __syncthreads();
  float h2 = b2[lane];
  for (int k = 0; k < 64; ++k) h2 = fmaf(sh[wave][k], w2[k * 64 + lane], h2);
  h2 = fmaxf(h2, 0.f);
  __syncthreads();
  sh[wave][lane] = h2;
  __syncthreads();
  float lg = -INFINITY;
  if (lane < 12) {
    lg = b3[lane];
    for (int k = 0; k < 64; ++k) lg = fmaf(sh[wave][k], w3[k * 12 + lane], lg);
  }
  float mx = lg;
  #pragma unroll
  for (int msk = 1; msk < 64; msk <<= 1) mx = fmaxf(mx, __shfl_xor(mx, msk));
  float ex = (lane < 12) ? __expf(lg - mx) : 0.f;
  float sm = ex;
  #pragma unroll
  for (int msk = 1; msk < 64; msk <<= 1) sm += __shfl_xor(sm, msk);
  if (ok && lane < 12) out[(size_t)r * 12 + lane] = ex / sm;
}

// ---------------- host ----------------
extern "C" void kernel_launch(void* const* d_in, const int* in_sizes, int n_in,
                              void* d_out, int out_size, void* d_ws, size_t ws_size,
                              hipStream_t stream) {
  const float* x    = (const float*)d_in[0];
  const int* edge   = (const int*)d_in[1];
  const int* batch  = (const int*)d_in[2];
  const float* W1l  = (const float*)d_in[3];
  const float* W1r  = (const float*)d_in[4];
  const float* a1   = (const float*)d_in[5];
  const float* b1   = (const float*)d_in[6];
  const float* W2l  = (const float*)d_in[7];
  const float* W2r  = (const float*)d_in[8];
  const float* a2   = (const float*)d_in[9];
  const float* b2   = (const float*)d_in[10];
  const float* W3l  = (const float*)d_in[11];
  const float* W3r  = (const float*)d_in[12];
  const float* a3   = (const float*)d_in[13];
  const float* b3   = (const float*)d_in[14];
  const float* lw1  = (const float*)d_in[15];
  const float* lb1  = (const float*)d_in[16];
  const float* lw2  = (const float*)d_in[17];
  const float* lb2  = (const float*)d_in[18];
  const float* lw3  = (const float*)d_in[19];
  const float* lb3  = (const float*)d_in[20];

  const int E = in_sizes[1] / 2;
  const int N = in_sizes[2];
  const int F0 = in_sizes[0] / N;   // 128
  const int G = out_size / 12;      // 512
  const int* src = edge;
  const int* dst = edge + E;

  // workspace carve (256B aligned)
  char* p = (char*)d_ws;
  auto alloc = [&](size_t bytes) { char* q = p; p += (bytes + 255) & ~(size_t)255; return q; };
  unsigned short* bufA = (unsigned short*)alloc((size_t)N * 256 * 2);
  unsigned short* bufB = (unsigned short*)alloc((size_t)N * 256 * 2);
  unsigned short* bufH = (unsigned short*)alloc((size_t)N * 256 * 2);
  unsigned short* WtL  = (unsigned short*)alloc(256 * 256 * 2);
  unsigned short* WtR  = (unsigned short*)alloc(256 * 256 * 2);
  int* counts   = (int*)alloc((size_t)N * 4);
  int* rowstart = (int*)alloc((size_t)(N + 1) * 4);
  int* cursor   = (int*)alloc((size_t)N * 4);
  int* bsums    = (int*)alloc(4096 * 4);
  int* boffs    = (int*)alloc(4096 * 4);
  int* dummy    = (int*)alloc(64 * 4);
  int* csr      = (int*)alloc((size_t)E * 4);
  float* gsum   = (float*)alloc((size_t)G * 64 * 4);
  int* gcnt     = (int*)alloc((size_t)G * 4);

  // ---- CSR by dst (built once, reused by all convs) ----
  hipMemsetAsync(counts, 0, (size_t)N * 4, stream);
  hist_kernel<<<(E + 255) / 256, 256, 0, stream>>>(dst, counts, E);
  int nb = (N + 255) / 256;
  scan_block<<<nb, 256, 0, stream>>>(counts, rowstart, bsums, N);
  scan_block<<<1, 256, 0, stream>>>(bsums, boffs, dummy, nb);
  scan_add<<<nb, 256, 0, stream>>>(rowstart, boffs, cursor, N, E);
  scatter_kernel<<<(E + 255) / 256, 256, 0, stream>>>(src, dst, cursor, csr, E);

  int gx = (N + 127) / 128;
  int ne = (N + 3) / 4;

  // ---- conv1: K=F0(128), Ncol=256, no self loops, relu; A = x (f32) ----
  convert_transpose<<<(F0 * 256 + 255) / 256, 256, 0, stream>>>(W1l, WtL, F0, 256);
  convert_transpose<<<(F0 * 256 + 255) / 256, 256, 0, stream>>>(W1r, WtR, F0, 256);
  gemm_dual<128, 2, 2, true><<<dim3(gx, 2, 2), 256, 0, stream>>>(x, WtL, WtR, bufA, bufB, N, F0, 256);
  edge_agg<4, false, true><<<ne, 256, 0, stream>>>(bufA, bufB, a1, b1, rowstart, csr, bufH, N);

  // ---- conv2: K=256, Ncol=256, self loops, relu; A = bufH (bf16) ----
  convert_transpose<<<(256 * 256 + 255) / 256, 256, 0, stream>>>(W2l, WtL, 256, 256);
  convert_transpose<<<(256 * 256 + 255) / 256, 256, 0, stream>>>(W2r, WtR, 256, 256);
  gemm_dual<128, 2, 2, false><<<dim3(gx, 2, 2), 256, 0, stream>>>(bufH, WtL, WtR, bufA, bufB, N, 256, 256);
  edge_agg<4, true, true><<<ne, 256, 0, stream>>>(bufA, bufB, a2, b2, rowstart, csr, bufH, N);

  // ---- conv3: K=256, Ncol=64, self loops, no relu; A = bufH (bf16) ----
  convert_transpose<<<(256 * 64 + 255) / 256, 256, 0, stream>>>(W3l, WtL, 256, 64);
  convert_transpose<<<(256 * 64 + 255) / 256, 256, 0, stream>>>(W3r, WtR, 256, 64);
  gemm_dual<64, 4, 1, false><<<dim3(gx, 1, 2), 256, 0, stream>>>(bufH, WtL, WtR, bufA, bufB, N, 256, 64);
  edge_agg<1, true, false><<<ne, 256, 0, stream>>>(bufA, bufB, a3, b3, rowstart, csr, bufH, N);

  // ---- global mean pool ----
  hipMemsetAsync(gsum, 0, (size_t)G * 64 * 4, stream);
  hipMemsetAsync(gcnt, 0, (size_t)G * 4, stream);
  pool_kernel<<<ne, 256, 0, stream>>>(bufH, batch, gsum, gcnt, N);

  // ---- MLP head + softmax ----
  mlp_kernel<<<(G + 3) / 4, 256, 0, stream>>>(gsum, gcnt, lw1, lb1, lw2, lb2, lw3, lb3,
                                              (float*)d_out, G);
}